// Round 3
// baseline (864.891 us; speedup 1.0000x reference)
//
#include <hip/hip_runtime.h>
#include <hip/hip_bf16.h>

// WindowAttention fully fused: B=2048 windows, N=98, C=192, H=6, hd=32, nw=64.
// K0: prep (o_w->f16, qkv_w->f16 with Q-rows pre-scaled, combined bias+mask f16 table).
// K1 (wa_fused): one block per window, 448 thr = 7 waves, everything through LDS:
//   P0 stage x->As f16 ; per head h: P1 QKV-gemm (B-frags direct from L2-resident wqh)
//   -> Qh/Kh/Vt LDS ; P2 QK^T + register softmax (cmb table) -> P ; P3 PV -> Ao LDS ;
//   P4 out-proj (w2 staged into dead As region, XOR-swizzled), fp32 out.
// HBM: x 154 MB in + out 154 MB out + ~8 MB tables. LDS 144.4 KB/block (1 block/CU).

#define NB   2048
#define NN   98
#define CC   192
#define NH   6
#define HD   32
#define SCALE 0.17677669529663687f   // 32^-0.5

typedef _Float16 half8 __attribute__((ext_vector_type(8)));
typedef _Float16 f16x4 __attribute__((ext_vector_type(4)));
typedef float    f32x4 __attribute__((ext_vector_type(4)));

__device__ __forceinline__ f32x4 mfma16(half8 a, half8 b, f32x4 c) {
    return __builtin_amdgcn_mfma_f32_16x16x32_f16(a, b, c, 0, 0, 0);
}

// ---------------- workspace layout (bytes) ----------------
// wqh f16 [576][192] (Q rows pre-scaled) :   221,184 @ 0
// w2  f16 [192][192]                     :    73,728 @ 221,184
// cmb f16 [64][6][98][98] (bias+mask)    : 7,375,872 @ 294,912    (total 7.67 MB)
#define WS_WQH 0ull
#define WS_W2  221184ull
#define WS_CMB 294912ull

// ---------------- K0: prep ----------------
__global__ __launch_bounds__(256) void wa_k0_prep(
    const float* __restrict__ o_w, const float* __restrict__ qkv_w,
    const float* __restrict__ mask, const float* __restrict__ bias_table,
    const int* __restrict__ rel_index,
    _Float16* __restrict__ w2, _Float16* __restrict__ wqh,
    _Float16* __restrict__ cmb)
{
    int t = blockIdx.x * 256 + threadIdx.x;
    if (t < CC * CC) {
        w2[t] = (_Float16)o_w[t];
    } else if (t < CC * CC + 3 * CC * CC) {
        int e = t - CC * CC;
        float v = qkv_w[e];
        if (e < CC * CC) v *= SCALE;             // fold attn scale into Q weights
        wqh[e] = (_Float16)v;
    } else if (t < CC * CC + 3 * CC * CC + 64 * NH * NN * NN) {
        int e  = t - 4 * CC * CC;                // ((w*6+h)*98+i)*98+j
        int wh = e / (NN * NN);
        int rr = e - wh * (NN * NN);
        int w  = wh / NH;
        int h  = wh - w * NH;
        cmb[e] = (_Float16)(mask[w * (NN * NN) + rr] +
                            bias_table[rel_index[rr] * NH + h]);
    }
}

// ---------------- fused attention kernel ----------------
__global__ __launch_bounds__(448) void wa_fused(
    const float* __restrict__ x, const _Float16* __restrict__ wqh,
    const float* __restrict__ qkv_b, const _Float16* __restrict__ w2,
    const float* __restrict__ o_b, const _Float16* __restrict__ cmb,
    float* __restrict__ out)
{
    const int b = blockIdx.x;
    const int widx = b & 63;

    __shared__ __align__(16) _Float16 As[112 * 200];  // x tile f16 (rows 98..111 zero); reused for w2 halves in P4
    __shared__ __align__(16) _Float16 Qh[112 * 40];   // Q (scale folded), stride 40
    __shared__ __align__(16) _Float16 Kh[112 * 40];
    __shared__ __align__(16) _Float16 Vt[32 * 128];   // V^T [d][i], XOR-swizzled chunks
    __shared__ __align__(16) _Float16 Pl[112 * 128];  // probs, XOR-swizzled chunks
    __shared__ __align__(16) _Float16 Ao[112 * 200];  // attention output [i][c]

    const int tid  = threadIdx.x;
    const int lane = tid & 63, wave = tid >> 6;       // wave = m-tile 0..6
    const int l16  = lane & 15, quad = lane >> 4;

    // ---- P0: stage x -> As (f16), zero pad rows; zero Vt/Pl pad chunks (k 112..127) ----
    const float* xb = x + (size_t)b * NN * CC;
    for (int idx = tid; idx < 2688; idx += 448) {     // 112 rows x 24 chunks, exactly 6 iters
        int row = idx / 24, g = idx - row * 24;
        half8 hv = {};
        if (row < NN) {
            const float* src = xb + row * CC + g * 8;
            float4 v0 = *(const float4*)src;
            float4 v1 = *(const float4*)(src + 4);
            hv = half8{(_Float16)v0.x, (_Float16)v0.y, (_Float16)v0.z, (_Float16)v0.w,
                       (_Float16)v1.x, (_Float16)v1.y, (_Float16)v1.z, (_Float16)v1.w};
        }
        *(half8*)(As + row * 200 + g * 8) = hv;
    }
    if (tid < 64) {                                   // Vt chunks 14,15 (cols 112..127) = 0
        int d = tid >> 1, c = 14 + (tid & 1);
        half8 z = {};
        *(half8*)(Vt + d * 128 + ((c ^ (d & 7)) << 3)) = z;
    }
    if (tid >= 64 && tid < 288) {                     // Pl chunks 14,15 rows 0..111 = 0
        int u = tid - 64;
        int row = u >> 1, c = 14 + (u & 1);
        half8 z = {};
        *(half8*)(Pl + row * 128 + ((c ^ (row & 7)) << 3)) = z;
    }
    __syncthreads();

    // ---- head loop ----
    for (int h = 0; h < NH; ++h) {
        // P1: Q/K/V gemm for head h. wave=mt; nt: 0,1=Q 2,3=K 4,5=V halves.
        half8 a[6];
        #pragma unroll
        for (int kk = 0; kk < 6; ++kk)
            a[kk] = *(const half8*)(As + (wave * 16 + l16) * 200 + kk * 32 + quad * 8);
        #pragma unroll
        for (int nt = 0; nt < 6; ++nt) {
            const int s  = nt >> 1, dh = (nt & 1) * 16;
            const int j  = s * CC + h * HD + dh + l16;      // qkv output col / wqh row
            const _Float16* bp = wqh + (size_t)j * CC + quad * 8;
            half8 bb[6];
            #pragma unroll
            for (int kk = 0; kk < 6; ++kk) bb[kk] = *(const half8*)(bp + kk * 32);
            f32x4 acc = {};
            #pragma unroll
            for (int kk = 0; kk < 6; ++kk) acc = mfma16(a[kk], bb[kk], acc);
            float bias = qkv_b[j];
            if (nt < 2) bias *= SCALE;                      // Q bias scaled (weights already are)
            const int i0 = wave * 16 + quad * 4;
            if (nt < 2) {
                #pragma unroll
                for (int r = 0; r < 4; ++r)
                    Qh[(i0 + r) * 40 + dh + l16] = (_Float16)(acc[r] + bias);
            } else if (nt < 4) {
                #pragma unroll
                for (int r = 0; r < 4; ++r)
                    Kh[(i0 + r) * 40 + dh + l16] = (_Float16)(acc[r] + bias);
            } else {
                f16x4 hv;
                #pragma unroll
                for (int r = 0; r < 4; ++r) hv[r] = (_Float16)(acc[r] + bias);
                int d = dh + l16;
                *(f16x4*)(Vt + d * 128 + (((i0 >> 3) ^ (d & 7)) << 3) + (i0 & 7)) = hv;
            }
        }
        __syncthreads();

        // P2: S = Q K^T (+cmb), register softmax, write Pl
        {
            half8 aq = *(const half8*)(Qh + (wave * 16 + l16) * 40 + quad * 8);
            f32x4 s[7];
            #pragma unroll
            for (int jt = 0; jt < 7; ++jt) {
                half8 bk = *(const half8*)(Kh + (jt * 16 + l16) * 40 + quad * 8);
                f32x4 z = {};
                s[jt] = mfma16(aq, bk, z);
            }
            const int i0 = wave * 16 + quad * 4;
            const _Float16* ct = cmb + (size_t)(widx * NH + h) * NN * NN;
            #pragma unroll
            for (int r = 0; r < 4; ++r) {
                int irc = i0 + r; if (irc > NN - 1) irc = NN - 1;
                const _Float16* cp = ct + irc * NN;
                #pragma unroll
                for (int jt = 0; jt < 7; ++jt) {
                    int jcol = jt * 16 + l16;
                    s[jt][r] = (jcol < NN) ? (s[jt][r] + (float)cp[jcol])
                                           : -__builtin_inff();
                }
            }
            #pragma unroll
            for (int r = 0; r < 4; ++r) {
                float mx = -__builtin_inff();
                #pragma unroll
                for (int jt = 0; jt < 7; ++jt) mx = fmaxf(mx, s[jt][r]);
                mx = fmaxf(mx, __shfl_xor(mx, 1));
                mx = fmaxf(mx, __shfl_xor(mx, 2));
                mx = fmaxf(mx, __shfl_xor(mx, 4));
                mx = fmaxf(mx, __shfl_xor(mx, 8));
                float sum = 0.f;
                #pragma unroll
                for (int jt = 0; jt < 7; ++jt) {
                    float p = __expf(s[jt][r] - mx);   // exp(-inf)=0 masks pad cols
                    s[jt][r] = p;
                    sum += p;
                }
                sum += __shfl_xor(sum, 1);
                sum += __shfl_xor(sum, 2);
                sum += __shfl_xor(sum, 4);
                sum += __shfl_xor(sum, 8);
                float inv = 1.0f / sum;
                int prow = i0 + r;
                #pragma unroll
                for (int jt = 0; jt < 7; ++jt) {
                    int c = jt * 2 + (l16 >> 3);       // chunk of col jcol
                    Pl[prow * 128 + ((c ^ (prow & 7)) << 3) + (l16 & 7)] =
                        (_Float16)(s[jt][r] * inv);
                }
            }
        }
        __syncthreads();

        // P3: O_h = P @ V -> Ao cols [h*32, h*32+32)
        #pragma unroll
        for (int ti = 0; ti < 2; ++ti) {
            int t = wave * 2 + ti, mt = t >> 1, nt = t & 1;
            int arow = mt * 16 + l16, brow = nt * 16 + l16;
            f32x4 acc = {};
            #pragma unroll
            for (int kc = 0; kc < 4; ++kc) {
                int c = kc * 4 + quad;
                half8 av = *(const half8*)(Pl + arow * 128 + ((c ^ (arow & 7)) << 3));
                half8 bv = *(const half8*)(Vt + brow * 128 + ((c ^ (brow & 7)) << 3));
                acc = mfma16(av, bv, acc);
            }
            #pragma unroll
            for (int r = 0; r < 4; ++r) {
                int i = mt * 16 + quad * 4 + r;
                Ao[i * 200 + h * HD + nt * 16 + l16] = (_Float16)acc[r];
            }
        }
        __syncthreads();
    }

    // ---- P4: out = Ao @ o_w^T + o_b ; w2 staged in halves into dead As region ----
    half8 a2[6];
    #pragma unroll
    for (int kk = 0; kk < 6; ++kk)
        a2[kk] = *(const half8*)(Ao + (wave * 16 + l16) * 200 + kk * 32 + quad * 8);
    const size_t outbase = (size_t)b * NN * CC;
    #pragma unroll
    for (int hh = 0; hh < 2; ++hh) {
        for (int idx = tid; idx < 2304; idx += 448) { // 96 rows x 24 chunks, XOR-swizzled
            int row = idx / 24, c = idx - row * 24;
            *(half8*)(As + row * CC + ((c ^ (row & 7)) << 3)) =
                *(const half8*)(w2 + (size_t)(hh * 96 + row) * CC + c * 8);
        }
        __syncthreads();
        #pragma unroll
        for (int nt = 0; nt < 6; ++nt) {
            const int erow = nt * 16 + l16;           // w2 row within half
            f32x4 acc = {};
            #pragma unroll
            for (int kk = 0; kk < 6; ++kk) {
                int c = kk * 4 + quad;
                half8 bb = *(const half8*)(As + erow * CC + ((c ^ (erow & 7)) << 3));
                acc = mfma16(a2[kk], bb, acc);
            }
            int e = hh * 96 + nt * 16 + l16;
            float ob = o_b[e];
            #pragma unroll
            for (int r = 0; r < 4; ++r) {
                int i = wave * 16 + quad * 4 + r;
                if (i < NN) out[outbase + (size_t)i * CC + e] = acc[r] + ob;
            }
        }
        if (hh == 0) __syncthreads();
    }
}

// ---------------- launcher ----------------
extern "C" void kernel_launch(void* const* d_in, const int* in_sizes, int n_in,
                              void* d_out, int out_size, void* d_ws, size_t ws_size,
                              hipStream_t stream)
{
    const float* x          = (const float*)d_in[0];
    const float* mask       = (const float*)d_in[1];
    const float* qkv_w      = (const float*)d_in[2];
    const float* qkv_b      = (const float*)d_in[3];
    const float* o_w        = (const float*)d_in[4];
    const float* o_b        = (const float*)d_in[5];
    const float* bias_table = (const float*)d_in[6];
    const int*   rel_index  = (const int*)d_in[7];

    char* ws = (char*)d_ws;
    _Float16* wqh = (_Float16*)(ws + WS_WQH);
    _Float16* w2  = (_Float16*)(ws + WS_W2);
    _Float16* cmb = (_Float16*)(ws + WS_CMB);
    float*    out = (float*)d_out;

    // K0: 36864 (w2) + 110592 (wqh) + 3687936 (cmb) elements
    const int k0n = 4 * CC * CC + 64 * NH * NN * NN;
    wa_k0_prep<<<(k0n + 255) / 256, 256, 0, stream>>>(
        o_w, qkv_w, mask, bias_table, rel_index, w2, wqh, cmb);
    // fused kernel: one block per window
    wa_fused<<<NB, 448, 0, stream>>>(x, wqh, qkv_b, w2, o_b, cmb, out);
}